// Round 9
// baseline (318.384 us; speedup 1.0000x reference)
//
#include <hip/hip_runtime.h>
#include <hip/hip_bf16.h>

typedef __hip_bfloat16 bf16;
typedef unsigned short u16;
typedef float f32x2 __attribute__((ext_vector_type(2)));

#define NC 8192
#define NF 32768
#define KNN 16
#define FMAXV 3.402823466e+38f

__device__ __forceinline__ float bfbits2f(u16 u){
  union { unsigned u; float f; } x; x.u = ((unsigned)u) << 16; return x.f;
}
__device__ __forceinline__ float asfloat(unsigned u){
  union { unsigned u; float f; } x; x.u = u; return x.f;
}
// packed fp32 fma: d = a*b + c on both halves (IEEE fma per half, bit-exact vs fmaf)
__device__ __forceinline__ f32x2 pk_fma(f32x2 a, f32x2 b, f32x2 c){
  f32x2 d;
  asm("v_pk_fma_f32 %0, %1, %2, %3" : "=v"(d) : "v"(a), "v"(b), "v"(c));
  return d;
}

// ---------- k_pw: fused k_prep + k_wprod + output tail copy (1028 + 64 + 128 = 1220 blocks) ----------
__global__ __launch_bounds__(256) void k_pw(const float* __restrict__ dpos,
                                            const float* __restrict__ W1,
                                            const float* __restrict__ W2,
                                            float4* __restrict__ posP,
                                            float4* __restrict__ W1eSa,
                                            float4* __restrict__ W1eSb,
                                            float4* __restrict__ W2Sa,
                                            float4* __restrict__ W2Sb,
                                            const float* __restrict__ Wk,
                                            const float* __restrict__ Wv,
                                            const float* __restrict__ Wq,
                                            const float* __restrict__ bk,
                                            const float* __restrict__ bv,
                                            const float* __restrict__ bq,
                                            float* __restrict__ WkqS,
                                            float* __restrict__ WvuS,
                                            float* __restrict__ bkq,
                                            float* __restrict__ bvu,
                                            float* __restrict__ wbq,
                                            float* __restrict__ sbq,
                                            const float* __restrict__ epos,
                                            const int* __restrict__ lab,
                                            float* __restrict__ out){
  __shared__ float partial[256];
  __shared__ float red[256];
  int gb = blockIdx.x, t = threadIdx.x;
  if (gb >= 1092){
    // ---- output tail copy (epos + labels) ----
    int gid = (gb - 1092) * 256 + t;
    if (gid < NF){
      float* op = out + (size_t)NF * 128;
      op[gid * 3 + 0] = epos[gid * 3 + 0];
      op[gid * 3 + 1] = epos[gid * 3 + 1];
      op[gid * 3 + 2] = epos[gid * 3 + 2];
      out[(size_t)NF * 128 + (size_t)NF * 3 + gid] = (float)lab[gid];
    }
    return;
  }
  if (gb >= 1028){
    // ---- prep part ----
    int g = (gb - 1028) * 256 + t;
    if (g < 4096){
      const float2* dp2 = (const float2*)(dpos + (size_t)g * 6);
      float2 a = dp2[0], b = dp2[1], c = dp2[2];
      float x0 = a.x, y0 = a.y, z0 = b.x;
      float x1 = b.y, y1 = c.x, z1 = c.y;
      float dd0 = __fadd_rn(__fadd_rn(__fmul_rn(x0,x0), __fmul_rn(y0,y0)), __fmul_rn(z0,z0));
      float dd1 = __fadd_rn(__fadd_rn(__fmul_rn(x1,x1), __fmul_rn(y1,y1)), __fmul_rn(z1,z1));
      posP[g * 2]     = make_float4(x0, x1, y0, y1);
      posP[g * 2 + 1] = make_float4(z0, z1, dd0 * 0.5f, dd1 * 0.5f);
    } else if (g >= 8192 && g < 10240){
      int f = g - 8192; int c4 = f >> 6, jg = f & 63;
      W1eSa[f] = ((const float4*)(W1 + (size_t)(2 * jg) * 384 + 256))[c4];
    } else if (g >= 10240 && g < 12288){
      int f = g - 10240; int c4 = f >> 6, jg = f & 63;
      W1eSb[f] = ((const float4*)(W1 + (size_t)(2 * jg + 1) * 384 + 256))[c4];
    } else if (g >= 12288 && g < 14336){
      int f = g - 12288; int c4 = f >> 6, jg = f & 63;
      W2Sa[f] = ((const float4*)(W2 + (size_t)(2 * jg) * 128))[c4];
    } else if (g >= 14336 && g < 16384){
      int f = g - 14336; int c4 = f >> 6, jg = f & 63;
      W2Sb[f] = ((const float4*)(W2 + (size_t)(2 * jg + 1) * 128))[c4];
    }
    return;
  }
  // ---- wprod part (4-way K-split) ----
  int B = gb;
  int csel = B >> 2, tch = B & 3;
  int o = (t & 63) + tch * 64;
  int q = t >> 6;
  int j0 = q * 64;
  if (csel < 128){
    int c = csel;
    float acc = 0.f;
    for (int j = j0; j < j0 + 64; ++j)
      acc = fmaf(Wk[(size_t)j * 256 + o], Wq[(size_t)j * 128 + c], acc);
    partial[t] = acc;
    if (tch == 0) red[t] = bk[t] * Wq[(size_t)t * 128 + c];
    __syncthreads();
    if (t < 64){
      float a = partial[t] + partial[t + 64] + partial[t + 128] + partial[t + 192];
      WkqS[(size_t)((o >> 2) * 128 + c) * 4 + (o & 3)] = a;
    }
    if (tch == 0){
      for (int s = 128; s > 0; s >>= 1){ if (t < s) red[t] += red[t + s]; __syncthreads(); }
      if (t == 0) bkq[c] = red[0];
    }
  } else if (csel < 256){
    int h = csel - 128;
    float acc = 0.f;
    for (int j = j0; j < j0 + 64; ++j)
      acc = fmaf(Wv[(size_t)j * 256 + o], W1[(size_t)h * 384 + j], acc);
    partial[t] = acc;
    if (tch == 0) red[t] = bv[t] * W1[(size_t)h * 384 + t];
    __syncthreads();
    if (t < 64){
      float a = partial[t] + partial[t + 64] + partial[t + 128] + partial[t + 192];
      WvuS[(size_t)((o >> 2) * 128 + h) * 4 + (o & 3)] = a;
    }
    if (tch == 0){
      for (int s = 128; s > 0; s >>= 1){ if (t < s) red[t] += red[t + s]; __syncthreads(); }
      if (t == 0) bvu[h] = red[0];
    }
  } else {
    float acc = 0.f;
    for (int j = j0; j < j0 + 64; ++j)
      acc = fmaf(Wk[(size_t)j * 256 + o], bq[j], acc);
    partial[t] = acc;
    if (tch == 0) red[t] = bk[t] * bq[t];
    __syncthreads();
    if (t < 64){
      float a = partial[t] + partial[t + 64] + partial[t + 128] + partial[t + 192];
      wbq[o] = a;
    }
    if (tch == 0){
      for (int s = 128; s > 0; s >>= 1){ if (t < s) red[t] += red[t + s]; __syncthreads(); }
      if (t == 0) sbq[0] = red[0];
    }
  }
}

// ---------- k_dk: fused k_dec + k_knn + k_e1, block-interleaved for CU co-residency ----------
// 7168 blocks, g%7: 0-3 knn (4096), 4 dec (1024), 5-6 e1 (2048).
// e1 blocks: E1 = bf16(ef@W1e + b1) -- pure streaming matmul, no LDS/barriers; fills knn's
// idle issue slots. dec memory-bound; knn VALU/latency-bound.
__global__ __launch_bounds__(256) void k_dk(const float* __restrict__ df,
                                            const float4* __restrict__ WkqS,
                                            const float4* __restrict__ WvuS,
                                            const float* __restrict__ bkq,
                                            const float* __restrict__ bvu,
                                            const float* __restrict__ wbq,
                                            const float* __restrict__ sbq,
                                            bf16* __restrict__ Zd, bf16* __restrict__ Ud,
                                            float* __restrict__ bqK,
                                            const float* __restrict__ epos,
                                            const float4* __restrict__ posP,
                                            int* __restrict__ knnI,
                                            const float* __restrict__ ef,
                                            const float4* __restrict__ W1eSa,
                                            const float4* __restrict__ W1eSb,
                                            const float* __restrict__ b1,
                                            bf16* __restrict__ E1){
  __shared__ float dpart[8][32];
  __shared__ float smin[8 * 64];
  __shared__ float tauLDS[8];
  __shared__ int   cntL[8][4];
  __shared__ float lval[8][4][64];
  __shared__ int   lidx[8][4][64];

  int g = blockIdx.x, t = threadIdx.x;
  int m = g % 7, q7 = g / 7;
  if (m >= 5){
    // ================= e1 path (block eb of 2048): E1 = bf16(ef@W1e + b1) =================
    int eb = q7 * 2 + (m - 5);
    int n0 = eb * 16;
    int jg = t & 63;
    int pg4 = (t >> 6) * 4;
    int j0 = jg * 2;
    float acc0[4], acc1[4];
    #pragma unroll
    for (int p = 0; p < 4; ++p){ acc0[p] = 0.f; acc1[p] = 0.f; }
    #pragma unroll 4
    for (int c4 = 0; c4 < 32; ++c4){
      float4 wa = W1eSa[c4 * 64 + jg];
      float4 wb = W1eSb[c4 * 64 + jg];
      #pragma unroll
      for (int p = 0; p < 4; ++p){
        float4 x = ((const float4*)(ef + (size_t)(n0 + pg4 + p) * 128))[c4];
        acc0[p] += wa.x*x.x + wa.y*x.y + wa.z*x.z + wa.w*x.w;
        acc1[p] += wb.x*x.x + wb.y*x.y + wb.z*x.z + wb.w*x.w;
      }
    }
    float b1a = b1[j0], b1b = b1[j0 + 1];
    #pragma unroll
    for (int p = 0; p < 4; ++p){
      size_t row = (size_t)(n0 + pg4 + p);
      bf16 ha = __float2bfloat16(acc0[p] + b1a);
      bf16 hb = __float2bfloat16(acc1[p] + b1b);
      ushort2 st; st.x = *(u16*)&ha; st.y = *(u16*)&hb;
      *(ushort2*)((u16*)E1 + row * 128 + j0) = st;
    }
    return;
  }
  if (m == 4){
    // ================= dec path (block q7 of 1024) =================
    int g0 = q7 * 8;
    int half = __builtin_amdgcn_readfirstlane(t >> 7);
    int c = t & 127;
    const float4* W = half ? WvuS : WkqS;
    float acc[8];
    #pragma unroll
    for (int p = 0; p < 8; ++p) acc[p] = 0.f;
    for (int j4 = 0; j4 < 64; ++j4){
      float4 w = W[j4 * 128 + c];
      #pragma unroll
      for (int p = 0; p < 8; ++p){
        float4 a = ((const float4*)(df + (size_t)(g0 + p) * 256))[j4];
        acc[p] += w.x*a.x + w.y*a.y + w.z*a.z + w.w*a.w;
      }
    }
    float bias = half ? bvu[c] : bkq[c];
    bf16* dst = half ? Ud : Zd;
    #pragma unroll
    for (int p = 0; p < 8; ++p)
      dst[(size_t)(g0 + p) * 128 + c] = __float2bfloat16(acc[p] + bias);
    {
      int r = t >> 5, seg = t & 31;
      float s = 0.f;
      const float* dr = df + (size_t)(g0 + r) * 256 + seg * 8;
      const float* wq = wbq + seg * 8;
      #pragma unroll
      for (int e = 0; e < 8; ++e) s = fmaf(dr[e], wq[e], s);
      dpart[r][seg] = s;
    }
    __syncthreads();
    if (t < 8){
      float s = sbq[0];
      #pragma unroll
      for (int seg = 0; seg < 32; ++seg) s += dpart[t][seg];
      bqK[g0 + t] = s;
    }
    return;
  }

  // ================= knn path (block kb of 4096) =================
  int kb = q7 * 4 + m;
  int lane = t & 63, w = t >> 6;
  int n0 = kb * 8;
  f32x2 nex2[8], ney2[8], nez2[8];
  #pragma unroll
  for (int p = 0; p < 8; ++p){
    float nx = -epos[(n0 + p) * 3 + 0];
    float ny = -epos[(n0 + p) * 3 + 1];
    float nz = -epos[(n0 + p) * 3 + 2];
    nex2[p].x = nx; nex2[p].y = nx;
    ney2[p].x = ny; ney2[p].y = ny;
    nez2[p].x = nz; nez2[p].y = nz;
  }
  const float4* base = posP + w * 2048;   // wave's 1024 candidate-pairs = 2048 float4

  // PASS A: per-lane minima over 2 packed candidates/iter (3 pk_fma + 2 min per point)
  f32x2 vmin2[8];
  #pragma unroll
  for (int p = 0; p < 8; ++p){ vmin2[p].x = FMAXV; vmin2[p].y = FMAXV; }
  #pragma unroll 4
  for (int s = 0; s < 16; ++s){
    int q2 = (s * 64 + lane) * 2;
    float4 XY = base[q2], ZW = base[q2 + 1];
    f32x2 X = {XY.x, XY.y}, Y = {XY.z, XY.w}, Z = {ZW.x, ZW.y}, W = {ZW.z, ZW.w};
    #pragma unroll
    for (int p = 0; p < 8; ++p){
      f32x2 v2 = pk_fma(nex2[p], X, W);
      v2 = pk_fma(ney2[p], Y, v2);
      v2 = pk_fma(nez2[p], Z, v2);
      vmin2[p].x = fminf(vmin2[p].x, v2.x);
      vmin2[p].y = fminf(vmin2[p].y, v2.y);
    }
  }
  float vmin[8];
  #pragma unroll
  for (int p = 0; p < 8; ++p) vmin[p] = fminf(vmin2[p].x, vmin2[p].y);

  // full bitonic sort of 64 lane-minima, 8 point-registers at once (lanes 0..15 -> ascending top-16)
  #pragma unroll
  for (int k = 2; k <= 64; k <<= 1){
    #pragma unroll
    for (int j = k >> 1; j > 0; j >>= 1){
      bool keepmin = ((lane & j) == 0) == ((lane & k) == 0);
      #pragma unroll
      for (int p = 0; p < 8; ++p){
        float pv = __shfl_xor(vmin[p], j);
        vmin[p] = keepmin ? fminf(vmin[p], pv) : fmaxf(vmin[p], pv);
      }
    }
  }
  if (lane < 16){
    #pragma unroll
    for (int p = 0; p < 8; ++p) smin[p * 64 + w * 16 + lane] = vmin[p];
  }
  __syncthreads();

  // union 17th-smallest for points 2w, 2w+1 (interleaved).
  {
    int src = (lane & 16) ? (lane ^ 15) : lane;
    float v0 = smin[(w * 2 + 0) * 64 + src];
    float v1 = smin[(w * 2 + 1) * 64 + src];
    #pragma unroll
    for (int j = 16; j > 0; j >>= 1){
      bool keepmin = ((lane & 32) == 0) == ((lane & j) == 0);
      float p0 = __shfl_xor(v0, j); v0 = keepmin ? fminf(v0, p0) : fmaxf(v0, p0);
      float p1 = __shfl_xor(v1, j); v1 = keepmin ? fminf(v1, p1) : fmaxf(v1, p1);
    }
    #pragma unroll
    for (int j = 32; j > 0; j >>= 1){
      bool keepmin = ((lane & j) == 0);
      float p0 = __shfl_xor(v0, j); v0 = keepmin ? fminf(v0, p0) : fmaxf(v0, p0);
      float p1 = __shfl_xor(v1, j); v1 = keepmin ? fminf(v1, p1) : fmaxf(v1, p1);
    }
    if (lane == 16){ tauLDS[w * 2] = v0; tauLDS[w * 2 + 1] = v1; }
  }
  __syncthreads();
  float tau0[8];
  #pragma unroll
  for (int p = 0; p < 8; ++p) tau0[p] = tauLDS[p];

  // PASS B: ballot + prefix-popcount append into per-wave private buffers
  unsigned long long lmlt = (1ull << lane) - 1ull;
  int cnt[8] = {0,0,0,0,0,0,0,0};
  #pragma unroll 2
  for (int s = 0; s < 16; ++s){
    int q = s * 64 + lane;
    float4 XY = base[q * 2], ZW = base[q * 2 + 1];
    f32x2 X = {XY.x, XY.y}, Y = {XY.z, XY.w}, Z = {ZW.x, ZW.y}, W = {ZW.z, ZW.w};
    int cand0 = w * 2048 + q * 2;
    #pragma unroll
    for (int p = 0; p < 8; ++p){
      f32x2 v2 = pk_fma(nex2[p], X, W);
      v2 = pk_fma(ney2[p], Y, v2);
      v2 = pk_fma(nez2[p], Z, v2);
      bool h0 = v2.x <= tau0[p];
      bool h1 = v2.y <= tau0[p];
      unsigned long long m0 = __ballot(h0);
      unsigned long long m1 = __ballot(h1);
      if (m0 | m1){   // wave-uniform skip
        int base0 = cnt[p];
        int c0 = (int)__popcll(m0);
        if (h0){
          int s0 = base0 + (int)__popcll(m0 & lmlt);
          if (s0 < 64){ lval[p][w][s0] = v2.x; lidx[p][w][s0] = cand0; }
        }
        if (h1){
          int s1 = base0 + c0 + (int)__popcll(m1 & lmlt);
          if (s1 < 64){ lval[p][w][s1] = v2.y; lidx[p][w][s1] = cand0 + 1; }
        }
        cnt[p] = base0 + c0 + (int)__popcll(m1);
      }
    }
  }
  if (lane == 0){
    #pragma unroll
    for (int p = 0; p < 8; ++p) cntL[p][w] = (cnt[p] > 64) ? 64 : cnt[p];
  }
  __syncthreads();

  // finalize points 2w, 2w+1 interleaved: gather from 4 private segments, exact select-16
  {
    int p0 = w * 2, p1 = w * 2 + 1;
    int nA = n0 + p0, nB = n0 + p1;
    int cA0 = cntL[p0][0], cA1 = cntL[p0][1], cA2 = cntL[p0][2], cA3 = cntL[p0][3];
    int cB0 = cntL[p1][0], cB1 = cntL[p1][1], cB2 = cntL[p1][2], cB3 = cntL[p1][3];
    int oA1 = cA0, oA2 = oA1 + cA1, oA3 = oA2 + cA2; int totA = oA3 + cA3; if (totA > 64) totA = 64;
    int oB1 = cB0, oB2 = oB1 + cB1, oB3 = oB2 + cB2; int totB = oB3 + cB3; if (totB > 64) totB = 64;
    int segA = (lane >= oA1) + (lane >= oA2) + (lane >= oA3);
    int segB = (lane >= oB1) + (lane >= oB2) + (lane >= oB3);
    int basA = segA == 0 ? 0 : (segA == 1 ? oA1 : (segA == 2 ? oA2 : oA3));
    int basB = segB == 0 ? 0 : (segB == 1 ? oB1 : (segB == 2 ? oB2 : oB3));
    float va = (lane < totA) ? lval[p0][segA][lane - basA] : FMAXV;
    int   ia = (lane < totA) ? lidx[p0][segA][lane - basA] : 0x7fffffff;
    float vb = (lane < totB) ? lval[p1][segB][lane - basB] : FMAXV;
    int   ib = (lane < totB) ? lidx[p1][segB][lane - basB] : 0x7fffffff;

    #pragma unroll
    for (int k = 2; k <= 16; k <<= 1){
      #pragma unroll
      for (int j = k >> 1; j > 0; j >>= 1){
        bool keepmin = ((lane & k) == 0) == ((lane & j) == 0);
        { float pv = __shfl_xor(va, j); int pid = __shfl_xor(ia, j);
          bool pl = (pv < va) || (pv == va && pid < ia);
          if (keepmin ? pl : !pl){ va = pv; ia = pid; } }
        { float pv = __shfl_xor(vb, j); int pid = __shfl_xor(ib, j);
          bool pl = (pv < vb) || (pv == vb && pid < ib);
          if (keepmin ? pl : !pl){ vb = pv; ib = pid; } }
      }
    }
    { float pv = __shfl_xor(va, 16); int pid = __shfl_xor(ia, 16);
      if ((pv < va) || (pv == va && pid < ia)){ va = pv; ia = pid; } }
    { float pv = __shfl_xor(vb, 16); int pid = __shfl_xor(ib, 16);
      if ((pv < vb) || (pv == vb && pid < ib)){ vb = pv; ib = pid; } }
    #pragma unroll
    for (int j = 8; j > 0; j >>= 1){
      bool keepmin = ((lane & 32) == 0) == ((lane & j) == 0);
      { float pv = __shfl_xor(va, j); int pid = __shfl_xor(ia, j);
        bool pl = (pv < va) || (pv == va && pid < ia);
        if (keepmin ? pl : !pl){ va = pv; ia = pid; } }
      { float pv = __shfl_xor(vb, j); int pid = __shfl_xor(ib, j);
        bool pl = (pv < vb) || (pv == vb && pid < ib);
        if (keepmin ? pl : !pl){ vb = pv; ib = pid; } }
    }
    { float pv = __shfl_xor(va, 32); int pid = __shfl_xor(ia, 32);
      if ((pv < va) || (pv == va && pid < ia)){ va = pv; ia = pid; } }
    { float pv = __shfl_xor(vb, 32); int pid = __shfl_xor(ib, 32);
      if ((pv < vb) || (pv == vb && pid < ib)){ vb = pv; ib = pid; } }

    if (lane < 16){
      knnI[(size_t)nA * 16 + lane] = ia;
      knnI[(size_t)nB * 16 + lane] = ib;
    }
  }
}

// ---------- k_amlp: fused attention read-out + (E1-based) MLP + LN ----------
// Score phase coalesced (round-8 verified): lane kk holds ef dims kk*8..+8; group walks
// the 16 neighbor Zd rows contiguously; reduce-scatter butterfly leaves neighbor kk's
// full score in lane kk. MLP1 reads precomputed E1 = bf16(ef@W1e + b1) from k_dk.
__global__ __launch_bounds__(256) void k_amlp(const int* __restrict__ knnI,
                                              const bf16* __restrict__ Zd,
                                              const bf16* __restrict__ Ud,
                                              const float* __restrict__ bqK,
                                              const float* __restrict__ ef,
                                              const bf16* __restrict__ E1,
                                              const float4* __restrict__ W2Sa,
                                              const float4* __restrict__ W2Sb,
                                              const float* __restrict__ b2,
                                              const float* __restrict__ lng, const float* __restrict__ lnb,
                                              float* __restrict__ out){
  __shared__ float haggL[16 * 128];
  __shared__ float hbuf[16 * 128];
  __shared__ float ubuf[16 * 128];
  __shared__ float stats[32];
  int t = threadIdx.x;
  int n0 = blockIdx.x * 16;
  int lane = t & 63, w = t >> 6;

  // ---- attention phase: point pp = w*4 + (lane>>4), neighbor slot kk = lane&15 ----
  {
    int kk = lane & 15;
    int pp = w * 4 + (lane >> 4);
    int n = n0 + pp;
    int ik = knnI[(size_t)n * 16 + kk];
    float bz = bqK[ik];
    // lane-local ef segment (dims kk*8 .. kk*8+7), coalesced 512B row read per group
    const float4* e4 = (const float4*)(ef + (size_t)n * 128 + kk * 8);
    float4 ea = e4[0], eb = e4[1];
    // broadcast the group's 16 neighbor indices
    int gbase = lane & 48;
    int ikk[16];
    #pragma unroll
    for (int k2 = 0; k2 < 16; ++k2) ikk[k2] = __shfl(ik, gbase | k2);
    // coalesced row reads -> per-lane partials qv[k2] = <ef_seg, Zd[ikk[k2]]_seg>
    float qv[16];
    {
      uint4 zb[8];
      #pragma unroll
      for (int k2 = 0; k2 < 8; ++k2) zb[k2] = *(const uint4*)((const u16*)Zd + (size_t)ikk[k2] * 128 + kk * 8);
      #pragma unroll
      for (int k2 = 0; k2 < 8; ++k2){
        uint4 z = zb[k2];
        float s;
        s = ea.x * asfloat(z.x << 16);
        s = fmaf(ea.y, asfloat(z.x & 0xffff0000u), s);
        s = fmaf(ea.z, asfloat(z.y << 16), s);
        s = fmaf(ea.w, asfloat(z.y & 0xffff0000u), s);
        s = fmaf(eb.x, asfloat(z.z << 16), s);
        s = fmaf(eb.y, asfloat(z.z & 0xffff0000u), s);
        s = fmaf(eb.z, asfloat(z.w << 16), s);
        s = fmaf(eb.w, asfloat(z.w & 0xffff0000u), s);
        qv[k2] = s;
      }
      #pragma unroll
      for (int k2 = 0; k2 < 8; ++k2) zb[k2] = *(const uint4*)((const u16*)Zd + (size_t)ikk[8 + k2] * 128 + kk * 8);
      #pragma unroll
      for (int k2 = 0; k2 < 8; ++k2){
        uint4 z = zb[k2];
        float s;
        s = ea.x * asfloat(z.x << 16);
        s = fmaf(ea.y, asfloat(z.x & 0xffff0000u), s);
        s = fmaf(ea.z, asfloat(z.y << 16), s);
        s = fmaf(ea.w, asfloat(z.y & 0xffff0000u), s);
        s = fmaf(eb.x, asfloat(z.z << 16), s);
        s = fmaf(eb.y, asfloat(z.z & 0xffff0000u), s);
        s = fmaf(eb.z, asfloat(z.w << 16), s);
        s = fmaf(eb.w, asfloat(z.w & 0xffff0000u), s);
        qv[8 + k2] = s;
      }
    }
    // reduce-scatter butterfly: stage m keeps elements e with (e&m)==(lane&m),
    // adding the partner's value of the SAME element.
    bool b1v = (lane & 1) != 0, b2v = (lane & 2) != 0, b4 = (lane & 4) != 0, b8 = (lane & 8) != 0;
    float q8[8];
    #pragma unroll
    for (int j = 0; j < 8; ++j){
      float keep = b1v ? qv[2*j+1] : qv[2*j];
      float send = b1v ? qv[2*j]   : qv[2*j+1];
      q8[j] = keep + __shfl_xor(send, 1);
    }
    float q4[4];
    #pragma unroll
    for (int j = 0; j < 4; ++j){
      float keep = b2v ? q8[2*j+1] : q8[2*j];
      float send = b2v ? q8[2*j]   : q8[2*j+1];
      q4[j] = keep + __shfl_xor(send, 2);
    }
    float q2[2];
    #pragma unroll
    for (int j = 0; j < 2; ++j){
      float keep = b4 ? q4[2*j+1] : q4[2*j];
      float send = b4 ? q4[2*j]   : q4[2*j+1];
      q2[j] = keep + __shfl_xor(send, 4);
    }
    float q1;
    {
      float keep = b8 ? q2[1] : q2[0];
      float send = b8 ? q2[0] : q2[1];
      q1 = keep + __shfl_xor(send, 8);
    }
    float sc = (q1 + bz) * (1.0f / 16.0f);
    float mx = sc;
    #pragma unroll
    for (int off = 1; off < 16; off <<= 1) mx = fmaxf(mx, __shfl_xor(mx, off));
    float e = __expf(sc - mx);
    float l = e;
    #pragma unroll
    for (int off = 1; off < 16; off <<= 1) l += __shfl_xor(l, off);
    float wgt = e / l;

    // agg: pre-broadcast weights, batched coalesced Ud row gathers
    float wk[16];
    #pragma unroll
    for (int k2 = 0; k2 < 16; ++k2) wk[k2] = __shfl(wgt, gbase | k2);
    float acc8[8];
    #pragma unroll
    for (int j = 0; j < 8; ++j) acc8[j] = 0.f;
    {
      uint4 ub[8];
      #pragma unroll
      for (int k2 = 0; k2 < 8; ++k2) ub[k2] = *(const uint4*)((const u16*)Ud + (size_t)ikk[k2] * 128 + kk * 8);
      #pragma unroll
      for (int k2 = 0; k2 < 8; ++k2){
        uint4 uu = ub[k2]; float wv = wk[k2];
        acc8[0] = fmaf(wv, asfloat(uu.x << 16), acc8[0]);
        acc8[1] = fmaf(wv, asfloat(uu.x & 0xffff0000u), acc8[1]);
        acc8[2] = fmaf(wv, asfloat(uu.y << 16), acc8[2]);
        acc8[3] = fmaf(wv, asfloat(uu.y & 0xffff0000u), acc8[3]);
        acc8[4] = fmaf(wv, asfloat(uu.z << 16), acc8[4]);
        acc8[5] = fmaf(wv, asfloat(uu.z & 0xffff0000u), acc8[5]);
        acc8[6] = fmaf(wv, asfloat(uu.w << 16), acc8[6]);
        acc8[7] = fmaf(wv, asfloat(uu.w & 0xffff0000u), acc8[7]);
      }
      #pragma unroll
      for (int k2 = 0; k2 < 8; ++k2) ub[k2] = *(const uint4*)((const u16*)Ud + (size_t)ikk[8 + k2] * 128 + kk * 8);
      #pragma unroll
      for (int k2 = 0; k2 < 8; ++k2){
        uint4 uu = ub[k2]; float wv = wk[8 + k2];
        acc8[0] = fmaf(wv, asfloat(uu.x << 16), acc8[0]);
        acc8[1] = fmaf(wv, asfloat(uu.x & 0xffff0000u), acc8[1]);
        acc8[2] = fmaf(wv, asfloat(uu.y << 16), acc8[2]);
        acc8[3] = fmaf(wv, asfloat(uu.y & 0xffff0000u), acc8[3]);
        acc8[4] = fmaf(wv, asfloat(uu.z << 16), acc8[4]);
        acc8[5] = fmaf(wv, asfloat(uu.z & 0xffff0000u), acc8[5]);
        acc8[6] = fmaf(wv, asfloat(uu.w << 16), acc8[6]);
        acc8[7] = fmaf(wv, asfloat(uu.w & 0xffff0000u), acc8[7]);
      }
    }
    float4* hp = (float4*)&haggL[pp * 128 + kk * 8];
    hp[0] = make_float4(acc8[0], acc8[1], acc8[2], acc8[3]);
    hp[1] = make_float4(acc8[4], acc8[5], acc8[6], acc8[7]);
  }

  // ---- MLP phase: h = relu(E1 + haggL); up = W2@h + b2; LN ----
  int jg = t & 63;
  int pg4 = __builtin_amdgcn_readfirstlane((t >> 6) * 4);
  int j0 = jg * 2;
  // prefetch E1 (independent of the haggL barrier)
  ushort2 ev[4];
  #pragma unroll
  for (int p = 0; p < 4; ++p)
    ev[p] = *(const ushort2*)((const u16*)E1 + (size_t)(n0 + pg4 + p) * 128 + j0);
  __syncthreads();   // haggL ready
  #pragma unroll
  for (int p = 0; p < 4; ++p){
    float2 hgv = *(const float2*)&haggL[(pg4 + p) * 128 + j0];
    hbuf[(pg4 + p) * 128 + j0]     = fmaxf(bfbits2f(ev[p].x) + hgv.x, 0.f);
    hbuf[(pg4 + p) * 128 + j0 + 1] = fmaxf(bfbits2f(ev[p].y) + hgv.y, 0.f);
  }
  __syncthreads();
  float acc2[2][4];
  #pragma unroll
  for (int a = 0; a < 2; ++a)
    #pragma unroll
    for (int p = 0; p < 4; ++p) acc2[a][p] = 0.f;
  const float4* hb4 = (const float4*)hbuf;
  #pragma unroll 4
  for (int c4 = 0; c4 < 32; ++c4){
    float4 wa = W2Sa[c4 * 64 + jg];
    float4 wb = W2Sb[c4 * 64 + jg];
    #pragma unroll
    for (int p = 0; p < 4; ++p){
      float4 x = hb4[(pg4 + p) * 32 + c4];
      acc2[0][p] += wa.x*x.x + wa.y*x.y + wa.z*x.z + wa.w*x.w;
      acc2[1][p] += wb.x*x.x + wb.y*x.y + wb.z*x.z + wb.w*x.w;
    }
  }
  float b2a = b2[j0], b2b = b2[j0 + 1];
  float u[2][4];
  #pragma unroll
  for (int p = 0; p < 4; ++p){
    u[0][p] = acc2[0][p] + b2a;
    u[1][p] = acc2[1][p] + b2b;
    ubuf[(pg4 + p) * 128 + j0]     = u[0][p];
    ubuf[(pg4 + p) * 128 + j0 + 1] = u[1][p];
  }
  __syncthreads();
  {
    int p = t >> 4, qi = t & 15;
    const float* ub = &ubuf[p * 128 + qi * 8];
    float s = 0.f, s2 = 0.f;
    #pragma unroll
    for (int e2i = 0; e2i < 8; ++e2i){ float v = ub[e2i]; s += v; s2 += v * v; }
    #pragma unroll
    for (int off = 1; off < 16; off <<= 1){ s += __shfl_xor(s, off); s2 += __shfl_xor(s2, off); }
    if (qi == 0){
      float mu = s * (1.f / 128.f);
      float var = s2 * (1.f / 128.f) - mu * mu;
      stats[p] = mu;
      stats[16 + p] = rsqrtf(fmaxf(var, 0.f) + 1e-5f);
    }
  }
  __syncthreads();
  float ga = lng[j0], gb = lng[j0 + 1];
  float ba = lnb[j0], bbv = lnb[j0 + 1];
  #pragma unroll
  for (int p = 0; p < 4; ++p){
    float mu = stats[pg4 + p], rs = stats[16 + pg4 + p];
    out[(size_t)(n0 + pg4 + p) * 128 + j0]     = (u[0][p] - mu) * rs * ga + ba;
    out[(size_t)(n0 + pg4 + p) * 128 + j0 + 1] = (u[1][p] - mu) * rs * gb + bbv;
  }
}

extern "C" void kernel_launch(void* const* d_in, const int* in_sizes, int n_in,
                              void* d_out, int out_size, void* d_ws, size_t ws_size,
                              hipStream_t stream){
  const float* df   = (const float*)d_in[0];
  const float* dpos = (const float*)d_in[1];
  const float* ef   = (const float*)d_in[2];
  const float* epos = (const float*)d_in[3];
  const int*   lab  = (const int*)d_in[4];
  const float* Wq = (const float*)d_in[5];
  const float* bq = (const float*)d_in[6];
  const float* Wk = (const float*)d_in[7];
  const float* bk = (const float*)d_in[8];
  const float* Wv = (const float*)d_in[9];
  const float* bv = (const float*)d_in[10];
  const float* W1 = (const float*)d_in[11];
  const float* b1 = (const float*)d_in[12];
  const float* W2 = (const float*)d_in[13];
  const float* b2 = (const float*)d_in[14];
  const float* lng = (const float*)d_in[15];
  const float* lnb = (const float*)d_in[16];
  float* out = (float*)d_out;

  // workspace layout (~15.3 MB)
  char* wsb = (char*)d_ws;
  float4* posP  = (float4*)(wsb);                    // 128 KB
  bf16*   Zd    = (bf16*)(wsb + 131072);             // 2 MB
  bf16*   Ud    = (bf16*)(wsb + 2228224);            // 2 MB
  float*  bqK   = (float*)(wsb + 4325376);           // 32 KB
  int*    knnI  = (int*)(wsb + 4358144);             // 2 MB (NF*16*4)
  bf16*   E1    = (bf16*)(wsb + 6455296);            // 8 MB (NF*128*2)
  float4* W1eSa = (float4*)(wsb + 14843904);         // 32 KB
  float4* W1eSb = (float4*)(wsb + 14876672);         // 32 KB
  float4* W2Sa  = (float4*)(wsb + 14909440);         // 32 KB
  float4* W2Sb  = (float4*)(wsb + 14942208);         // 32 KB
  float*  WkqS  = (float*)(wsb + 14974976);          // 128 KB
  float*  WvuS  = (float*)(wsb + 15106048);          // 128 KB
  float*  bkq   = (float*)(wsb + 15237120);          // 512 B
  float*  bvu   = (float*)(wsb + 15237632);          // 512 B
  float*  wbq   = (float*)(wsb + 15238144);          // 1 KB
  float*  sbq   = (float*)(wsb + 15239168);          // 4 B

  k_pw   <<<1220, 256, 0, stream>>>(dpos, W1, W2, posP, W1eSa, W1eSb, W2Sa, W2Sb,
                                    Wk, Wv, Wq, bk, bv, bq, WkqS, WvuS, bkq, bvu, wbq, sbq,
                                    epos, lab, out);
  k_dk   <<<7168, 256, 0, stream>>>(df, (const float4*)WkqS, (const float4*)WvuS, bkq, bvu, wbq, sbq,
                                    Zd, Ud, bqK, epos, posP, knnI,
                                    ef, W1eSa, W1eSb, b1, E1);
  k_amlp <<<NF / 16, 256, 0, stream>>>(knnI, Zd, Ud, bqK, ef, E1, W2Sa, W2Sb, b2, lng, lnb, out);
  (void)in_sizes; (void)n_in; (void)out_size; (void)ws_size;
}

// Round 10
// 300.912 us; speedup vs baseline: 1.0581x; 1.0581x over previous
//
#include <hip/hip_runtime.h>
#include <hip/hip_bf16.h>

typedef __hip_bfloat16 bf16;
typedef unsigned short u16;
typedef float f32x2 __attribute__((ext_vector_type(2)));

#define NC 8192
#define NF 32768
#define KNN 16
#define FMAXV 3.402823466e+38f

__device__ __forceinline__ float bfbits2f(u16 u){
  union { unsigned u; float f; } x; x.u = ((unsigned)u) << 16; return x.f;
}
__device__ __forceinline__ float asfloat(unsigned u){
  union { unsigned u; float f; } x; x.u = u; return x.f;
}
// packed fp32 fma: d = a*b + c on both halves (IEEE fma per half, bit-exact vs fmaf)
__device__ __forceinline__ f32x2 pk_fma(f32x2 a, f32x2 b, f32x2 c){
  f32x2 d;
  asm("v_pk_fma_f32 %0, %1, %2, %3" : "=v"(d) : "v"(a), "v"(b), "v"(c));
  return d;
}

// ---------- k_pw: fused k_prep + k_wprod + output tail copy (1028 + 64 + 128 = 1220 blocks) ----------
__global__ __launch_bounds__(256) void k_pw(const float* __restrict__ dpos,
                                            const float* __restrict__ W1,
                                            const float* __restrict__ W2,
                                            float4* __restrict__ posP,
                                            float4* __restrict__ W1eSa,
                                            float4* __restrict__ W1eSb,
                                            float4* __restrict__ W2Sa,
                                            float4* __restrict__ W2Sb,
                                            const float* __restrict__ Wk,
                                            const float* __restrict__ Wv,
                                            const float* __restrict__ Wq,
                                            const float* __restrict__ bk,
                                            const float* __restrict__ bv,
                                            const float* __restrict__ bq,
                                            float* __restrict__ WkqS,
                                            float* __restrict__ WvuS,
                                            float* __restrict__ bkq,
                                            float* __restrict__ bvu,
                                            float* __restrict__ wbq,
                                            float* __restrict__ sbq,
                                            const float* __restrict__ epos,
                                            const int* __restrict__ lab,
                                            float* __restrict__ out){
  __shared__ float partial[256];
  __shared__ float red[256];
  int gb = blockIdx.x, t = threadIdx.x;
  if (gb >= 1092){
    // ---- output tail copy (epos + labels) ----
    int gid = (gb - 1092) * 256 + t;
    if (gid < NF){
      float* op = out + (size_t)NF * 128;
      op[gid * 3 + 0] = epos[gid * 3 + 0];
      op[gid * 3 + 1] = epos[gid * 3 + 1];
      op[gid * 3 + 2] = epos[gid * 3 + 2];
      out[(size_t)NF * 128 + (size_t)NF * 3 + gid] = (float)lab[gid];
    }
    return;
  }
  if (gb >= 1028){
    // ---- prep part ----
    int g = (gb - 1028) * 256 + t;
    if (g < 4096){
      const float2* dp2 = (const float2*)(dpos + (size_t)g * 6);
      float2 a = dp2[0], b = dp2[1], c = dp2[2];
      float x0 = a.x, y0 = a.y, z0 = b.x;
      float x1 = b.y, y1 = c.x, z1 = c.y;
      float dd0 = __fadd_rn(__fadd_rn(__fmul_rn(x0,x0), __fmul_rn(y0,y0)), __fmul_rn(z0,z0));
      float dd1 = __fadd_rn(__fadd_rn(__fmul_rn(x1,x1), __fmul_rn(y1,y1)), __fmul_rn(z1,z1));
      posP[g * 2]     = make_float4(x0, x1, y0, y1);
      posP[g * 2 + 1] = make_float4(z0, z1, dd0 * 0.5f, dd1 * 0.5f);
    } else if (g >= 8192 && g < 10240){
      int f = g - 8192; int c4 = f >> 6, jg = f & 63;
      W1eSa[f] = ((const float4*)(W1 + (size_t)(2 * jg) * 384 + 256))[c4];
    } else if (g >= 10240 && g < 12288){
      int f = g - 10240; int c4 = f >> 6, jg = f & 63;
      W1eSb[f] = ((const float4*)(W1 + (size_t)(2 * jg + 1) * 384 + 256))[c4];
    } else if (g >= 12288 && g < 14336){
      int f = g - 12288; int c4 = f >> 6, jg = f & 63;
      W2Sa[f] = ((const float4*)(W2 + (size_t)(2 * jg) * 128))[c4];
    } else if (g >= 14336 && g < 16384){
      int f = g - 14336; int c4 = f >> 6, jg = f & 63;
      W2Sb[f] = ((const float4*)(W2 + (size_t)(2 * jg + 1) * 128))[c4];
    }
    return;
  }
  // ---- wprod part (4-way K-split) ----
  int B = gb;
  int csel = B >> 2, tch = B & 3;
  int o = (t & 63) + tch * 64;
  int q = t >> 6;
  int j0 = q * 64;
  if (csel < 128){
    int c = csel;
    float acc = 0.f;
    for (int j = j0; j < j0 + 64; ++j)
      acc = fmaf(Wk[(size_t)j * 256 + o], Wq[(size_t)j * 128 + c], acc);
    partial[t] = acc;
    if (tch == 0) red[t] = bk[t] * Wq[(size_t)t * 128 + c];
    __syncthreads();
    if (t < 64){
      float a = partial[t] + partial[t + 64] + partial[t + 128] + partial[t + 192];
      WkqS[(size_t)((o >> 2) * 128 + c) * 4 + (o & 3)] = a;
    }
    if (tch == 0){
      for (int s = 128; s > 0; s >>= 1){ if (t < s) red[t] += red[t + s]; __syncthreads(); }
      if (t == 0) bkq[c] = red[0];
    }
  } else if (csel < 256){
    int h = csel - 128;
    float acc = 0.f;
    for (int j = j0; j < j0 + 64; ++j)
      acc = fmaf(Wv[(size_t)j * 256 + o], W1[(size_t)h * 384 + j], acc);
    partial[t] = acc;
    if (tch == 0) red[t] = bv[t] * W1[(size_t)h * 384 + t];
    __syncthreads();
    if (t < 64){
      float a = partial[t] + partial[t + 64] + partial[t + 128] + partial[t + 192];
      WvuS[(size_t)((o >> 2) * 128 + h) * 4 + (o & 3)] = a;
    }
    if (tch == 0){
      for (int s = 128; s > 0; s >>= 1){ if (t < s) red[t] += red[t + s]; __syncthreads(); }
      if (t == 0) bvu[h] = red[0];
    }
  } else {
    float acc = 0.f;
    for (int j = j0; j < j0 + 64; ++j)
      acc = fmaf(Wk[(size_t)j * 256 + o], bq[j], acc);
    partial[t] = acc;
    if (tch == 0) red[t] = bk[t] * bq[t];
    __syncthreads();
    if (t < 64){
      float a = partial[t] + partial[t + 64] + partial[t + 128] + partial[t + 192];
      wbq[o] = a;
    }
    if (tch == 0){
      for (int s = 128; s > 0; s >>= 1){ if (t < s) red[t] += red[t + s]; __syncthreads(); }
      if (t == 0) sbq[0] = red[0];
    }
  }
}

// ---------- k_dk: fused k_dec + k_knn, block-interleaved (round-8 verified, reverted) ----------
__global__ __launch_bounds__(256) void k_dk(const float* __restrict__ df,
                                            const float4* __restrict__ WkqS,
                                            const float4* __restrict__ WvuS,
                                            const float* __restrict__ bkq,
                                            const float* __restrict__ bvu,
                                            const float* __restrict__ wbq,
                                            const float* __restrict__ sbq,
                                            bf16* __restrict__ Zd, bf16* __restrict__ Ud,
                                            float* __restrict__ bqK,
                                            const float* __restrict__ epos,
                                            const float4* __restrict__ posP,
                                            int* __restrict__ knnI){
  __shared__ float dpart[8][32];
  __shared__ float smin[8 * 64];
  __shared__ float tauLDS[8];
  __shared__ int   cntL[8][4];
  __shared__ float lval[8][4][64];
  __shared__ int   lidx[8][4][64];

  int g = blockIdx.x, t = threadIdx.x;
  int m = g % 5, q5 = g / 5;
  if (m == 4){
    // ================= dec path (block q5 of 1024) =================
    int g0 = q5 * 8;
    int half = __builtin_amdgcn_readfirstlane(t >> 7);
    int c = t & 127;
    const float4* W = half ? WvuS : WkqS;
    float acc[8];
    #pragma unroll
    for (int p = 0; p < 8; ++p) acc[p] = 0.f;
    for (int j4 = 0; j4 < 64; ++j4){
      float4 w = W[j4 * 128 + c];
      #pragma unroll
      for (int p = 0; p < 8; ++p){
        float4 a = ((const float4*)(df + (size_t)(g0 + p) * 256))[j4];
        acc[p] += w.x*a.x + w.y*a.y + w.z*a.z + w.w*a.w;
      }
    }
    float bias = half ? bvu[c] : bkq[c];
    bf16* dst = half ? Ud : Zd;
    #pragma unroll
    for (int p = 0; p < 8; ++p)
      dst[(size_t)(g0 + p) * 128 + c] = __float2bfloat16(acc[p] + bias);
    {
      int r = t >> 5, seg = t & 31;
      float s = 0.f;
      const float* dr = df + (size_t)(g0 + r) * 256 + seg * 8;
      const float* wq = wbq + seg * 8;
      #pragma unroll
      for (int e = 0; e < 8; ++e) s = fmaf(dr[e], wq[e], s);
      dpart[r][seg] = s;
    }
    __syncthreads();
    if (t < 8){
      float s = sbq[0];
      #pragma unroll
      for (int seg = 0; seg < 32; ++seg) s += dpart[t][seg];
      bqK[g0 + t] = s;
    }
    return;
  }

  // ================= knn path (block kb of 4096) =================
  int kb = q5 * 4 + m;
  int lane = t & 63, w = t >> 6;
  int n0 = kb * 8;
  f32x2 nex2[8], ney2[8], nez2[8];
  #pragma unroll
  for (int p = 0; p < 8; ++p){
    float nx = -epos[(n0 + p) * 3 + 0];
    float ny = -epos[(n0 + p) * 3 + 1];
    float nz = -epos[(n0 + p) * 3 + 2];
    nex2[p].x = nx; nex2[p].y = nx;
    ney2[p].x = ny; ney2[p].y = ny;
    nez2[p].x = nz; nez2[p].y = nz;
  }
  const float4* base = posP + w * 2048;   // wave's 1024 candidate-pairs = 2048 float4

  // PASS A: per-lane minima over 2 packed candidates/iter (3 pk_fma + 2 min per point)
  f32x2 vmin2[8];
  #pragma unroll
  for (int p = 0; p < 8; ++p){ vmin2[p].x = FMAXV; vmin2[p].y = FMAXV; }
  #pragma unroll 4
  for (int s = 0; s < 16; ++s){
    int q2 = (s * 64 + lane) * 2;
    float4 XY = base[q2], ZW = base[q2 + 1];
    f32x2 X = {XY.x, XY.y}, Y = {XY.z, XY.w}, Z = {ZW.x, ZW.y}, W = {ZW.z, ZW.w};
    #pragma unroll
    for (int p = 0; p < 8; ++p){
      f32x2 v2 = pk_fma(nex2[p], X, W);
      v2 = pk_fma(ney2[p], Y, v2);
      v2 = pk_fma(nez2[p], Z, v2);
      vmin2[p].x = fminf(vmin2[p].x, v2.x);
      vmin2[p].y = fminf(vmin2[p].y, v2.y);
    }
  }
  float vmin[8];
  #pragma unroll
  for (int p = 0; p < 8; ++p) vmin[p] = fminf(vmin2[p].x, vmin2[p].y);

  // full bitonic sort of 64 lane-minima, 8 point-registers at once (lanes 0..15 -> ascending top-16)
  #pragma unroll
  for (int k = 2; k <= 64; k <<= 1){
    #pragma unroll
    for (int j = k >> 1; j > 0; j >>= 1){
      bool keepmin = ((lane & j) == 0) == ((lane & k) == 0);
      #pragma unroll
      for (int p = 0; p < 8; ++p){
        float pv = __shfl_xor(vmin[p], j);
        vmin[p] = keepmin ? fminf(vmin[p], pv) : fmaxf(vmin[p], pv);
      }
    }
  }
  if (lane < 16){
    #pragma unroll
    for (int p = 0; p < 8; ++p) smin[p * 64 + w * 16 + lane] = vmin[p];
  }
  __syncthreads();

  // union 17th-smallest for points 2w, 2w+1 (interleaved).
  {
    int src = (lane & 16) ? (lane ^ 15) : lane;
    float v0 = smin[(w * 2 + 0) * 64 + src];
    float v1 = smin[(w * 2 + 1) * 64 + src];
    #pragma unroll
    for (int j = 16; j > 0; j >>= 1){
      bool keepmin = ((lane & 32) == 0) == ((lane & j) == 0);
      float p0 = __shfl_xor(v0, j); v0 = keepmin ? fminf(v0, p0) : fmaxf(v0, p0);
      float p1 = __shfl_xor(v1, j); v1 = keepmin ? fminf(v1, p1) : fmaxf(v1, p1);
    }
    #pragma unroll
    for (int j = 32; j > 0; j >>= 1){
      bool keepmin = ((lane & j) == 0);
      float p0 = __shfl_xor(v0, j); v0 = keepmin ? fminf(v0, p0) : fmaxf(v0, p0);
      float p1 = __shfl_xor(v1, j); v1 = keepmin ? fminf(v1, p1) : fmaxf(v1, p1);
    }
    if (lane == 16){ tauLDS[w * 2] = v0; tauLDS[w * 2 + 1] = v1; }
  }
  __syncthreads();
  float tau0[8];
  #pragma unroll
  for (int p = 0; p < 8; ++p) tau0[p] = tauLDS[p];

  // PASS B: ballot + prefix-popcount append into per-wave private buffers
  unsigned long long lmlt = (1ull << lane) - 1ull;
  int cnt[8] = {0,0,0,0,0,0,0,0};
  #pragma unroll 2
  for (int s = 0; s < 16; ++s){
    int q = s * 64 + lane;
    float4 XY = base[q * 2], ZW = base[q * 2 + 1];
    f32x2 X = {XY.x, XY.y}, Y = {XY.z, XY.w}, Z = {ZW.x, ZW.y}, W = {ZW.z, ZW.w};
    int cand0 = w * 2048 + q * 2;
    #pragma unroll
    for (int p = 0; p < 8; ++p){
      f32x2 v2 = pk_fma(nex2[p], X, W);
      v2 = pk_fma(ney2[p], Y, v2);
      v2 = pk_fma(nez2[p], Z, v2);
      bool h0 = v2.x <= tau0[p];
      bool h1 = v2.y <= tau0[p];
      unsigned long long m0 = __ballot(h0);
      unsigned long long m1 = __ballot(h1);
      if (m0 | m1){   // wave-uniform skip
        int base0 = cnt[p];
        int c0 = (int)__popcll(m0);
        if (h0){
          int s0 = base0 + (int)__popcll(m0 & lmlt);
          if (s0 < 64){ lval[p][w][s0] = v2.x; lidx[p][w][s0] = cand0; }
        }
        if (h1){
          int s1 = base0 + c0 + (int)__popcll(m1 & lmlt);
          if (s1 < 64){ lval[p][w][s1] = v2.y; lidx[p][w][s1] = cand0 + 1; }
        }
        cnt[p] = base0 + c0 + (int)__popcll(m1);
      }
    }
  }
  if (lane == 0){
    #pragma unroll
    for (int p = 0; p < 8; ++p) cntL[p][w] = (cnt[p] > 64) ? 64 : cnt[p];
  }
  __syncthreads();

  // finalize points 2w, 2w+1 interleaved: gather from 4 private segments, exact select-16
  {
    int p0 = w * 2, p1 = w * 2 + 1;
    int nA = n0 + p0, nB = n0 + p1;
    int cA0 = cntL[p0][0], cA1 = cntL[p0][1], cA2 = cntL[p0][2], cA3 = cntL[p0][3];
    int cB0 = cntL[p1][0], cB1 = cntL[p1][1], cB2 = cntL[p1][2], cB3 = cntL[p1][3];
    int oA1 = cA0, oA2 = oA1 + cA1, oA3 = oA2 + cA2; int totA = oA3 + cA3; if (totA > 64) totA = 64;
    int oB1 = cB0, oB2 = oB1 + cB1, oB3 = oB2 + cB2; int totB = oB3 + cB3; if (totB > 64) totB = 64;
    int segA = (lane >= oA1) + (lane >= oA2) + (lane >= oA3);
    int segB = (lane >= oB1) + (lane >= oB2) + (lane >= oB3);
    int basA = segA == 0 ? 0 : (segA == 1 ? oA1 : (segA == 2 ? oA2 : oA3));
    int basB = segB == 0 ? 0 : (segB == 1 ? oB1 : (segB == 2 ? oB2 : oB3));
    float va = (lane < totA) ? lval[p0][segA][lane - basA] : FMAXV;
    int   ia = (lane < totA) ? lidx[p0][segA][lane - basA] : 0x7fffffff;
    float vb = (lane < totB) ? lval[p1][segB][lane - basB] : FMAXV;
    int   ib = (lane < totB) ? lidx[p1][segB][lane - basB] : 0x7fffffff;

    #pragma unroll
    for (int k = 2; k <= 16; k <<= 1){
      #pragma unroll
      for (int j = k >> 1; j > 0; j >>= 1){
        bool keepmin = ((lane & k) == 0) == ((lane & j) == 0);
        { float pv = __shfl_xor(va, j); int pid = __shfl_xor(ia, j);
          bool pl = (pv < va) || (pv == va && pid < ia);
          if (keepmin ? pl : !pl){ va = pv; ia = pid; } }
        { float pv = __shfl_xor(vb, j); int pid = __shfl_xor(ib, j);
          bool pl = (pv < vb) || (pv == vb && pid < ib);
          if (keepmin ? pl : !pl){ vb = pv; ib = pid; } }
      }
    }
    { float pv = __shfl_xor(va, 16); int pid = __shfl_xor(ia, 16);
      if ((pv < va) || (pv == va && pid < ia)){ va = pv; ia = pid; } }
    { float pv = __shfl_xor(vb, 16); int pid = __shfl_xor(ib, 16);
      if ((pv < vb) || (pv == vb && pid < ib)){ vb = pv; ib = pid; } }
    #pragma unroll
    for (int j = 8; j > 0; j >>= 1){
      bool keepmin = ((lane & 32) == 0) == ((lane & j) == 0);
      { float pv = __shfl_xor(va, j); int pid = __shfl_xor(ia, j);
        bool pl = (pv < va) || (pv == va && pid < ia);
        if (keepmin ? pl : !pl){ va = pv; ia = pid; } }
      { float pv = __shfl_xor(vb, j); int pid = __shfl_xor(ib, j);
        bool pl = (pv < vb) || (pv == vb && pid < ib);
        if (keepmin ? pl : !pl){ vb = pv; ib = pid; } }
    }
    { float pv = __shfl_xor(va, 32); int pid = __shfl_xor(ia, 32);
      if ((pv < va) || (pv == va && pid < ia)){ va = pv; ia = pid; } }
    { float pv = __shfl_xor(vb, 32); int pid = __shfl_xor(ib, 32);
      if ((pv < vb) || (pv == vb && pid < ib)){ vb = pv; ib = pid; } }

    if (lane < 16){
      knnI[(size_t)nA * 16 + lane] = ia;
      knnI[(size_t)nB * 16 + lane] = ib;
    }
  }
}

// ---------- k_amlp: BARRIER-FREE wave-autonomous attention + MLP + LN ----------
// All LDS rows (haggL, hbuf) are wave-private: wave w writes/reads only rows 4w..4w+3.
// Within-wave ds_write -> ds_read ordering is guaranteed by lgkmcnt; no __syncthreads
// anywhere, so each wave flows through attention -> MLP1 -> MLP2 -> LN independently and
// different waves' gather latencies hide under each other's FMA phases.
// LN computed fully in registers via 64-lane butterfly (each wave owns its 4 points).
__global__ __launch_bounds__(256) void k_amlp(const int* __restrict__ knnI,
                                              const bf16* __restrict__ Zd,
                                              const bf16* __restrict__ Ud,
                                              const float* __restrict__ bqK,
                                              const float* __restrict__ ef,
                                              const float4* __restrict__ W1eSa,
                                              const float4* __restrict__ W1eSb,
                                              const float* __restrict__ b1,
                                              const float4* __restrict__ W2Sa,
                                              const float4* __restrict__ W2Sb,
                                              const float* __restrict__ b2,
                                              const float* __restrict__ lng, const float* __restrict__ lnb,
                                              float* __restrict__ out){
  __shared__ float haggL[16 * 128];
  __shared__ float hbuf[16 * 128];
  int t = threadIdx.x;
  int n0 = blockIdx.x * 16;
  int lane = t & 63, w = t >> 6;

  // ---- attention phase: point pp = w*4 + (lane>>4), neighbor slot kk = lane&15 ----
  {
    int kk = lane & 15;
    int pp = w * 4 + (lane >> 4);
    int n = n0 + pp;
    int ik = knnI[(size_t)n * 16 + kk];
    float bz = bqK[ik];
    const float4* e4 = (const float4*)(ef + (size_t)n * 128 + kk * 8);
    float4 ea = e4[0], eb = e4[1];
    int gbase = lane & 48;
    int ikk[16];
    #pragma unroll
    for (int k2 = 0; k2 < 16; ++k2) ikk[k2] = __shfl(ik, gbase | k2);
    // coalesced row reads -> per-lane partials qv[k2] = <ef_seg, Zd[ikk[k2]]_seg>
    float qv[16];
    {
      uint4 zb[8];
      #pragma unroll
      for (int k2 = 0; k2 < 8; ++k2) zb[k2] = *(const uint4*)((const u16*)Zd + (size_t)ikk[k2] * 128 + kk * 8);
      #pragma unroll
      for (int k2 = 0; k2 < 8; ++k2){
        uint4 z = zb[k2];
        float s;
        s = ea.x * asfloat(z.x << 16);
        s = fmaf(ea.y, asfloat(z.x & 0xffff0000u), s);
        s = fmaf(ea.z, asfloat(z.y << 16), s);
        s = fmaf(ea.w, asfloat(z.y & 0xffff0000u), s);
        s = fmaf(eb.x, asfloat(z.z << 16), s);
        s = fmaf(eb.y, asfloat(z.z & 0xffff0000u), s);
        s = fmaf(eb.z, asfloat(z.w << 16), s);
        s = fmaf(eb.w, asfloat(z.w & 0xffff0000u), s);
        qv[k2] = s;
      }
      #pragma unroll
      for (int k2 = 0; k2 < 8; ++k2) zb[k2] = *(const uint4*)((const u16*)Zd + (size_t)ikk[8 + k2] * 128 + kk * 8);
      #pragma unroll
      for (int k2 = 0; k2 < 8; ++k2){
        uint4 z = zb[k2];
        float s;
        s = ea.x * asfloat(z.x << 16);
        s = fmaf(ea.y, asfloat(z.x & 0xffff0000u), s);
        s = fmaf(ea.z, asfloat(z.y << 16), s);
        s = fmaf(ea.w, asfloat(z.y & 0xffff0000u), s);
        s = fmaf(eb.x, asfloat(z.z << 16), s);
        s = fmaf(eb.y, asfloat(z.z & 0xffff0000u), s);
        s = fmaf(eb.z, asfloat(z.w << 16), s);
        s = fmaf(eb.w, asfloat(z.w & 0xffff0000u), s);
        qv[8 + k2] = s;
      }
    }
    // reduce-scatter butterfly (round-8 verified): stage m keeps elements e with
    // (e&m)==(lane&m), adding the partner's value of the SAME element.
    bool b1v = (lane & 1) != 0, b2v = (lane & 2) != 0, b4 = (lane & 4) != 0, b8 = (lane & 8) != 0;
    float q8[8];
    #pragma unroll
    for (int j = 0; j < 8; ++j){
      float keep = b1v ? qv[2*j+1] : qv[2*j];
      float send = b1v ? qv[2*j]   : qv[2*j+1];
      q8[j] = keep + __shfl_xor(send, 1);
    }
    float q4[4];
    #pragma unroll
    for (int j = 0; j < 4; ++j){
      float keep = b2v ? q8[2*j+1] : q8[2*j];
      float send = b2v ? q8[2*j]   : q8[2*j+1];
      q4[j] = keep + __shfl_xor(send, 2);
    }
    float q2[2];
    #pragma unroll
    for (int j = 0; j < 2; ++j){
      float keep = b4 ? q4[2*j+1] : q4[2*j];
      float send = b4 ? q4[2*j]   : q4[2*j+1];
      q2[j] = keep + __shfl_xor(send, 4);
    }
    float q1;
    {
      float keep = b8 ? q2[1] : q2[0];
      float send = b8 ? q2[0] : q2[1];
      q1 = keep + __shfl_xor(send, 8);
    }
    float sc = (q1 + bz) * (1.0f / 16.0f);
    float mx = sc;
    #pragma unroll
    for (int off = 1; off < 16; off <<= 1) mx = fmaxf(mx, __shfl_xor(mx, off));
    float e = __expf(sc - mx);
    float l = e;
    #pragma unroll
    for (int off = 1; off < 16; off <<= 1) l += __shfl_xor(l, off);
    float wgt = e / l;

    // agg: pre-broadcast weights, batched coalesced Ud row gathers
    float wk[16];
    #pragma unroll
    for (int k2 = 0; k2 < 16; ++k2) wk[k2] = __shfl(wgt, gbase | k2);
    float acc8[8];
    #pragma unroll
    for (int j = 0; j < 8; ++j) acc8[j] = 0.f;
    {
      uint4 ub[8];
      #pragma unroll
      for (int k2 = 0; k2 < 8; ++k2) ub[k2] = *(const uint4*)((const u16*)Ud + (size_t)ikk[k2] * 128 + kk * 8);
      #pragma unroll
      for (int k2 = 0; k2 < 8; ++k2){
        uint4 uu = ub[k2]; float wv = wk[k2];
        acc8[0] = fmaf(wv, asfloat(uu.x << 16), acc8[0]);
        acc8[1] = fmaf(wv, asfloat(uu.x & 0xffff0000u), acc8[1]);
        acc8[2] = fmaf(wv, asfloat(uu.y << 16), acc8[2]);
        acc8[3] = fmaf(wv, asfloat(uu.y & 0xffff0000u), acc8[3]);
        acc8[4] = fmaf(wv, asfloat(uu.z << 16), acc8[4]);
        acc8[5] = fmaf(wv, asfloat(uu.z & 0xffff0000u), acc8[5]);
        acc8[6] = fmaf(wv, asfloat(uu.w << 16), acc8[6]);
        acc8[7] = fmaf(wv, asfloat(uu.w & 0xffff0000u), acc8[7]);
      }
      #pragma unroll
      for (int k2 = 0; k2 < 8; ++k2) ub[k2] = *(const uint4*)((const u16*)Ud + (size_t)ikk[8 + k2] * 128 + kk * 8);
      #pragma unroll
      for (int k2 = 0; k2 < 8; ++k2){
        uint4 uu = ub[k2]; float wv = wk[8 + k2];
        acc8[0] = fmaf(wv, asfloat(uu.x << 16), acc8[0]);
        acc8[1] = fmaf(wv, asfloat(uu.x & 0xffff0000u), acc8[1]);
        acc8[2] = fmaf(wv, asfloat(uu.y << 16), acc8[2]);
        acc8[3] = fmaf(wv, asfloat(uu.y & 0xffff0000u), acc8[3]);
        acc8[4] = fmaf(wv, asfloat(uu.z << 16), acc8[4]);
        acc8[5] = fmaf(wv, asfloat(uu.z & 0xffff0000u), acc8[5]);
        acc8[6] = fmaf(wv, asfloat(uu.w << 16), acc8[6]);
        acc8[7] = fmaf(wv, asfloat(uu.w & 0xffff0000u), acc8[7]);
      }
    }
    float4* hp = (float4*)&haggL[pp * 128 + kk * 8];   // wave-private rows 4w..4w+3
    hp[0] = make_float4(acc8[0], acc8[1], acc8[2], acc8[3]);
    hp[1] = make_float4(acc8[4], acc8[5], acc8[6], acc8[7]);
  }
  // NO barrier: haggL rows are wave-private; lgkmcnt orders write->read within the wave.

  // ---- MLP1: acc = ef@W1e; h = relu(acc + b1 + haggL) -> hbuf (own rows) ----
  int jg = t & 63;
  int pg4 = __builtin_amdgcn_readfirstlane((t >> 6) * 4);
  int j0 = jg * 2;
  float acc[2][4];
  #pragma unroll
  for (int a = 0; a < 2; ++a)
    #pragma unroll
    for (int p = 0; p < 4; ++p) acc[a][p] = 0.f;
  #pragma unroll 4
  for (int c4 = 0; c4 < 32; ++c4){
    float4 wa = W1eSa[c4 * 64 + jg];
    float4 wb = W1eSb[c4 * 64 + jg];
    #pragma unroll
    for (int p = 0; p < 4; ++p){
      float4 x = ((const float4*)(ef + (size_t)(n0 + pg4 + p) * 128))[c4];
      acc[0][p] += wa.x*x.x + wa.y*x.y + wa.z*x.z + wa.w*x.w;
      acc[1][p] += wb.x*x.x + wb.y*x.y + wb.z*x.z + wb.w*x.w;
    }
  }
  float b1a = b1[j0], b1b = b1[j0 + 1];
  #pragma unroll
  for (int p = 0; p < 4; ++p){
    float2 hgv = *(const float2*)&haggL[(pg4 + p) * 128 + j0];
    hbuf[(pg4 + p) * 128 + j0]     = fmaxf(acc[0][p] + b1a + hgv.x, 0.f);
    hbuf[(pg4 + p) * 128 + j0 + 1] = fmaxf(acc[1][p] + b1b + hgv.y, 0.f);
  }
  // NO barrier: hbuf rows are wave-private.

  // ---- MLP2: up = W2@h + b2 (hbuf read wave-uniform, own rows) ----
  float acc2[2][4];
  #pragma unroll
  for (int a = 0; a < 2; ++a)
    #pragma unroll
    for (int p = 0; p < 4; ++p) acc2[a][p] = 0.f;
  const float4* hb4 = (const float4*)hbuf;
  #pragma unroll 4
  for (int c4 = 0; c4 < 32; ++c4){
    float4 wa = W2Sa[c4 * 64 + jg];
    float4 wb = W2Sb[c4 * 64 + jg];
    #pragma unroll
    for (int p = 0; p < 4; ++p){
      float4 x = hb4[(pg4 + p) * 32 + c4];
      acc2[0][p] += wa.x*x.x + wa.y*x.y + wa.z*x.z + wa.w*x.w;
      acc2[1][p] += wb.x*x.x + wb.y*x.y + wb.z*x.z + wb.w*x.w;
    }
  }
  float b2a = b2[j0], b2b = b2[j0 + 1];
  float u0[4], u1[4];
  #pragma unroll
  for (int p = 0; p < 4; ++p){
    u0[p] = acc2[0][p] + b2a;
    u1[p] = acc2[1][p] + b2b;
  }

  // ---- LayerNorm fully in registers: 64-lane butterfly, 4 points per wave ----
  float s[4], s2[4];
  #pragma unroll
  for (int p = 0; p < 4; ++p){
    s[p]  = u0[p] + u1[p];
    s2[p] = u0[p]*u0[p] + u1[p]*u1[p];
  }
  #pragma unroll
  for (int off = 1; off < 64; off <<= 1){
    #pragma unroll
    for (int p = 0; p < 4; ++p){
      s[p]  += __shfl_xor(s[p],  off);
      s2[p] += __shfl_xor(s2[p], off);
    }
  }
  float ga = lng[j0], gb = lng[j0 + 1];
  float ba = lnb[j0], bbv = lnb[j0 + 1];
  #pragma unroll
  for (int p = 0; p < 4; ++p){
    float mu  = s[p] * (1.f / 128.f);
    float var = s2[p] * (1.f / 128.f) - mu * mu;
    float rs  = rsqrtf(fmaxf(var, 0.f) + 1e-5f);
    out[(size_t)(n0 + pg4 + p) * 128 + j0]     = (u0[p] - mu) * rs * ga + ba;
    out[(size_t)(n0 + pg4 + p) * 128 + j0 + 1] = (u1[p] - mu) * rs * gb + bbv;
  }
}

extern "C" void kernel_launch(void* const* d_in, const int* in_sizes, int n_in,
                              void* d_out, int out_size, void* d_ws, size_t ws_size,
                              hipStream_t stream){
  const float* df   = (const float*)d_in[0];
  const float* dpos = (const float*)d_in[1];
  const float* ef   = (const float*)d_in[2];
  const float* epos = (const float*)d_in[3];
  const int*   lab  = (const int*)d_in[4];
  const float* Wq = (const float*)d_in[5];
  const float* bq = (const float*)d_in[6];
  const float* Wk = (const float*)d_in[7];
  const float* bk = (const float*)d_in[8];
  const float* Wv = (const float*)d_in[9];
  const float* bv = (const float*)d_in[10];
  const float* W1 = (const float*)d_in[11];
  const float* b1 = (const float*)d_in[12];
  const float* W2 = (const float*)d_in[13];
  const float* b2 = (const float*)d_in[14];
  const float* lng = (const float*)d_in[15];
  const float* lnb = (const float*)d_in[16];
  float* out = (float*)d_out;

  // workspace layout (~13.2 MB)
  char* wsb = (char*)d_ws;
  float4* posP  = (float4*)(wsb);                    // 128 KB
  bf16*   Zd    = (bf16*)(wsb + 131072);             // 2 MB
  bf16*   Ud    = (bf16*)(wsb + 2228224);            // 2 MB
  float*  bqK   = (float*)(wsb + 4325376);           // 32 KB
  int*    knnI  = (int*)(wsb + 4358144);             // 2 MB (NF*16*4)
  float4* W1eSa = (float4*)(wsb + 12746752);         // 32 KB
  float4* W1eSb = (float4*)(wsb + 12779520);         // 32 KB
  float4* W2Sa  = (float4*)(wsb + 12812288);         // 32 KB
  float4* W2Sb  = (float4*)(wsb + 12845056);         // 32 KB
  float*  WkqS  = (float*)(wsb + 12877824);          // 128 KB
  float*  WvuS  = (float*)(wsb + 13008896);          // 128 KB
  float*  bkq   = (float*)(wsb + 13139968);          // 512 B
  float*  bvu   = (float*)(wsb + 13140480);          // 512 B
  float*  wbq   = (float*)(wsb + 13140992);          // 1 KB
  float*  sbq   = (float*)(wsb + 13142016);          // 4 B

  k_pw   <<<1220, 256, 0, stream>>>(dpos, W1, W2, posP, W1eSa, W1eSb, W2Sa, W2Sb,
                                    Wk, Wv, Wq, bk, bv, bq, WkqS, WvuS, bkq, bvu, wbq, sbq,
                                    epos, lab, out);
  k_dk   <<<5120, 256, 0, stream>>>(df, (const float4*)WkqS, (const float4*)WvuS, bkq, bvu, wbq, sbq,
                                    Zd, Ud, bqK, epos, posP, knnI);
  k_amlp <<<NF / 16, 256, 0, stream>>>(knnI, Zd, Ud, bqK, ef, W1eSa, W1eSb, b1, W2Sa, W2Sb, b2, lng, lnb, out);
  (void)in_sizes; (void)n_in; (void)out_size; (void)ws_size;
}